// Round 9
// baseline (312.027 us; speedup 1.0000x reference)
//
#include <hip/hip_runtime.h>

#define N 4096            // row length
#define NEG_BIG -9999999.9f
#define CAPW 64           // per-wave candidate capacity

// v8: z-less discriminating experiment (Model A: duty/reg-limited vs
// Model B: generic ~2.6 TB/s read-service cap).
//  - ONE ROW PER WAVE, 256-thr blocks (4 waves), 2048 blocks = 8/CU ->
//    up to 32 waves/CU. Zero barriers (same-wave LDS program order,
//    validated rounds 2-4).
//  - Phase 1: PURE STREAMING row-max. No z[] retention: frees ~32 VGPRs so
//    the compiler can hold ~8 float4 loads in flight per wave (vs ~4 when
//    z[32] squeezed the budget to 44 regs).
//  - Phase 2: only lanes with lane_max > rmax-1 (expected ~1-3 of 64)
//    re-read their 16 KB (L1/L2-hot, fetched microseconds ago) and pack
//    candidates w = z-rmax with positions into static regs (rule #20).
//  - Newton on <=8 broadcast reg candidates (sentinel -2); LDS-list Newton
//    for K in 9..64; ovf/all-masked rows re-read per iteration (L2-hot,
//    rare) with butterfly reductions.
//  - Output: round-5 best structure -- hipMemsetAsync zeros + <=4 scatter
//    stores per lane; full-row store only on ovf fallback.
__global__ __launch_bounds__(256)
void sparsemax_kernel(const float* __restrict__ x,
                      const float* __restrict__ m,
                      float* __restrict__ out,
                      int rows)
{
    const int lane = (int)threadIdx.x & 63;
    const int wid  = (int)threadIdx.x >> 6;       // 0..3
    const int row  = blockIdx.x * 4 + wid;        // one row per wave

    __shared__ float cand[4][CAPW];
    __shared__ int   cnt[4];

    if (row >= rows) return;                      // wave-uniform
    if (lane == 0) cnt[wid] = 0;                  // same-wave ordering

    const size_t base = (size_t)row * (N / 4);
    const float4* __restrict__ xr = (const float4*)x + base;
    const float4* __restrict__ mr = (const float4*)m + base;

    // ---- Phase 1: streaming masked-max over the row (16 float4/lane/stream).
    // z = (mask ? x : NEG_BIG) * 2   (/(1-TEMP), TEMP=0.5)
    float lmax = -3.0e38f;
#pragma unroll
    for (int jb = 0; jb < 16; jb += 4) {
        float4 xv0 = xr[(jb + 0) * 64 + lane];
        float4 xv1 = xr[(jb + 1) * 64 + lane];
        float4 xv2 = xr[(jb + 2) * 64 + lane];
        float4 xv3 = xr[(jb + 3) * 64 + lane];
        float4 mv0 = mr[(jb + 0) * 64 + lane];
        float4 mv1 = mr[(jb + 1) * 64 + lane];
        float4 mv2 = mr[(jb + 2) * 64 + lane];
        float4 mv3 = mr[(jb + 3) * 64 + lane];
#define SPMAX_MAX4(xv, mv)                                                  \
        {                                                                   \
            float z0 = (mv.x != 0.0f ? xv.x : NEG_BIG) * 2.0f;              \
            float z1 = (mv.y != 0.0f ? xv.y : NEG_BIG) * 2.0f;              \
            float z2 = (mv.z != 0.0f ? xv.z : NEG_BIG) * 2.0f;              \
            float z3 = (mv.w != 0.0f ? xv.w : NEG_BIG) * 2.0f;              \
            lmax = fmaxf(lmax, fmaxf(fmaxf(z0, z1), fmaxf(z2, z3)));        \
        }
        SPMAX_MAX4(xv0, mv0)
        SPMAX_MAX4(xv1, mv1)
        SPMAX_MAX4(xv2, mv2)
        SPMAX_MAX4(xv3, mv3)
#undef SPMAX_MAX4
    }

    // Wave-wide max butterfly (whole row lives in this wave).
    float rmax = lmax;
#pragma unroll
    for (int k = 32; k >= 1; k >>= 1)
        rmax = fmaxf(rmax, __shfl_xor(rmax, k, 64));

    // ---- Phase 2: candidate pack, only for lanes that can hold one.
    // Support subset: sum_support(z - tau) = 1 => tau >= rmax - 1, and
    // candidates are exactly {z > rmax - 1}. Re-reads are L1/L2-hot.
    const float thr0 = rmax - 1.0f;
    float lc0 = 0.0f, lc1 = 0.0f, lc2 = 0.0f, lc3 = 0.0f;
    int   lp0 = 0,    lp1 = 0,    lp2 = 0,    lp3 = 0;
    int lcnt = 0;
    if (lmax > thr0) {                            // ~1-3 lanes of 64
#pragma unroll
        for (int j = 0; j < 16; ++j) {
            float4 xv = xr[j * 64 + lane];
            float4 mv = mr[j * 64 + lane];
            float zs[4];
            zs[0] = (mv.x != 0.0f ? xv.x : NEG_BIG) * 2.0f;
            zs[1] = (mv.y != 0.0f ? xv.y : NEG_BIG) * 2.0f;
            zs[2] = (mv.z != 0.0f ? xv.z : NEG_BIG) * 2.0f;
            zs[3] = (mv.w != 0.0f ? xv.w : NEG_BIG) * 2.0f;
#pragma unroll
            for (int c = 0; c < 4; ++c) {
                if (zs[c] > thr0) {
                    float w = zs[c] - rmax;
                    int col = (j * 64 + lane) * 4 + c;
                    lc0 = (lcnt == 0) ? w   : lc0;
                    lp0 = (lcnt == 0) ? col : lp0;
                    lc1 = (lcnt == 1) ? w   : lc1;
                    lp1 = (lcnt == 1) ? col : lp1;
                    lc2 = (lcnt == 2) ? w   : lc2;
                    lp2 = (lcnt == 2) ? col : lp2;
                    lc3 = (lcnt == 3) ? w   : lc3;
                    lp3 = (lcnt == 3) ? col : lp3;
                    ++lcnt;
                }
            }
        }
    }
    // One LDS atomic per lane-with-candidates; same-wave program order makes
    // the list writes visible before the cnt read below.
    int basei = 0;
    if (lcnt > 0) basei = atomicAdd(&cnt[wid], lcnt);
    if (lcnt > 0 && basei + 0 < CAPW) cand[wid][basei + 0] = lc0;
    if (lcnt > 1 && basei + 1 < CAPW) cand[wid][basei + 1] = lc1;
    if (lcnt > 2 && basei + 2 < CAPW) cand[wid][basei + 2] = lc2;
    if (lcnt > 3 && basei + 3 < CAPW) cand[wid][basei + 3] = lc3;

    const int  K   = cnt[wid];                    // wave-uniform
    const bool ovf = __any(lcnt > 4) || (K > CAPW);
    float u = -1.0f;                              // solve sum max(w-u,0)=1

    if (!ovf && K <= 8) {
        // Broadcast candidates to registers; sentinel -2.0f never active
        // since u >= -1 throughout (v = -2 - u <= -1 < 0).
        float c0 = (0 < K) ? cand[wid][0] : -2.0f;
        float c1 = (1 < K) ? cand[wid][1] : -2.0f;
        float c2 = (2 < K) ? cand[wid][2] : -2.0f;
        float c3 = (3 < K) ? cand[wid][3] : -2.0f;
        float c4 = (4 < K) ? cand[wid][4] : -2.0f;
        float c5 = (5 < K) ? cand[wid][5] : -2.0f;
        float c6 = (6 < K) ? cand[wid][6] : -2.0f;
        float c7 = (7 < K) ? cand[wid][7] : -2.0f;
        for (int it = 0; it < 32; ++it) {
            float s = 0.0f, c = 0.0f;
#define SPMAX_ACC(cc) { float v = (cc) - u; if (v > 0.0f) { s += v; c += 1.0f; } }
            SPMAX_ACC(c0) SPMAX_ACC(c1) SPMAX_ACC(c2) SPMAX_ACC(c3)
            SPMAX_ACC(c4) SPMAX_ACC(c5) SPMAX_ACC(c6) SPMAX_ACC(c7)
#undef SPMAX_ACC
            float un = u + (s - 1.0f) / c;        // monotone non-decreasing
            if (!(un > u)) break;                 // exact fixed point
            u = un;
        }
    } else if (!ovf) {
        // Fat row: Newton over the LDS candidate list (broadcast reads).
        for (int it = 0; it < 32; ++it) {
            float s = 0.0f, c = 0.0f;
            for (int j = 0; j < K; ++j) {
                float v = cand[wid][j] - u;
                if (v > 0.0f) { s += v; c += 1.0f; }
            }
            float un = u + (s - 1.0f) / c;
            if (!(un > u)) break;
            u = un;
        }
    } else {
        // Overflow (incl. all-masked: every w==0 > -1 -> all 64 elems are
        // candidates -> ovf). Newton with per-iteration re-reads (L2-hot,
        // rare rows only) + butterfly reductions. Wave-uniform break.
        for (int it = 0; it < 32; ++it) {
            float s = 0.0f, c = 0.0f;
#pragma unroll 4
            for (int j = 0; j < 16; ++j) {
                float4 xv = xr[j * 64 + lane];
                float4 mv = mr[j * 64 + lane];
                float z0 = (mv.x != 0.0f ? xv.x : NEG_BIG) * 2.0f;
                float z1 = (mv.y != 0.0f ? xv.y : NEG_BIG) * 2.0f;
                float z2 = (mv.z != 0.0f ? xv.z : NEG_BIG) * 2.0f;
                float z3 = (mv.w != 0.0f ? xv.w : NEG_BIG) * 2.0f;
                float v;
                v = (z0 - rmax) - u; if (v > 0.0f) { s += v; c += 1.0f; }
                v = (z1 - rmax) - u; if (v > 0.0f) { s += v; c += 1.0f; }
                v = (z2 - rmax) - u; if (v > 0.0f) { s += v; c += 1.0f; }
                v = (z3 - rmax) - u; if (v > 0.0f) { s += v; c += 1.0f; }
            }
#pragma unroll
            for (int k = 32; k >= 1; k >>= 1) {
                s += __shfl_xor(s, k, 64);
                c += __shfl_xor(c, k, 64);
            }
            float un = u + (s - 1.0f) / c;
            if (!(un > u)) break;
            u = un;
        }
    }

    if (!ovf) {
        // Scatter only the positive support entries; memset provided zeros.
        // out value = z - tau = (w + rmax) - (rmax + u) = w - u.
        float* __restrict__ orow = out + (size_t)row * N;
        if (lcnt > 0) { float v = lc0 - u; if (v > 0.0f) orow[lp0] = v; }
        if (lcnt > 1) { float v = lc1 - u; if (v > 0.0f) orow[lp1] = v; }
        if (lcnt > 2) { float v = lc2 - u; if (v > 0.0f) orow[lp2] = v; }
        if (lcnt > 3) { float v = lc3 - u; if (v > 0.0f) orow[lp3] = v; }
    } else {
        // Full-row store fallback (re-read, L2-hot). All-masked: live=0.
        const float live = (rmax == NEG_BIG * 2.0f) ? 0.0f : 1.0f;
        const float thr  = rmax + u;              // = tau
        float4* __restrict__ outr = (float4*)out + base;
#pragma unroll 4
        for (int j = 0; j < 16; ++j) {
            float4 xv = xr[j * 64 + lane];
            float4 mv = mr[j * 64 + lane];
            float4 o;
            o.x = fmaxf((mv.x != 0.0f ? xv.x : NEG_BIG) * 2.0f - thr, 0.0f) * live;
            o.y = fmaxf((mv.y != 0.0f ? xv.y : NEG_BIG) * 2.0f - thr, 0.0f) * live;
            o.z = fmaxf((mv.z != 0.0f ? xv.z : NEG_BIG) * 2.0f - thr, 0.0f) * live;
            o.w = fmaxf((mv.w != 0.0f ? xv.w : NEG_BIG) * 2.0f - thr, 0.0f) * live;
            outr[j * 64 + lane] = o;
        }
    }
}

extern "C" void kernel_launch(void* const* d_in, const int* in_sizes, int n_in,
                              void* d_out, int out_size, void* d_ws, size_t ws_size,
                              hipStream_t stream) {
    const float* x = (const float*)d_in[0];
    const float* m = (const float*)d_in[1];
    float* out = (float*)d_out;
    const int rows = in_sizes[0] / N;             // 8192
    // Output is ~99.9% zeros: zero-fill at pure-write BW, then the kernel
    // scatter-writes only the support entries (round-5 best structure).
    hipMemsetAsync(d_out, 0, (size_t)out_size, stream);
    const int nblk = (rows + 3) / 4;              // 2048 blocks x 4 waves
    sparsemax_kernel<<<nblk, 256, 0, stream>>>(x, m, out, rows);
}

// Round 10
// 304.981 us; speedup vs baseline: 1.0231x; 1.0231x over previous
//
#include <hip/hip_runtime.h>

#define N 4096            // row length
#define NEG_BIG -9999999.9f
#define CAP 256           // candidate buffer capacity per row

// v10: burst-load experiment on the round-5 best (memset + scatter, 104 us).
// Little's-law model across rounds 0-9: app read BW == waves/CU x in-flight
// bytes/wave / ~230ns, pinned at 2.3-2.6 TB/s because the r0/r5 interleaved
// load->consume loop keeps only ~2-4 float4 loads in flight (VGPR 44-48).
// Change: issue ALL 16 loads (8 xv + 8 mv) into distinct registers BEFORE
// any consumption -> ~256B/wave in flight at the proven-best residency
// (8192x128 grid, ~15 waves/CU). Everything else identical to round 5.
//  - VGPR prediction ~80-96 (the clustering signature; ~50 would mean the
//    compiler re-interleaved and the experiment is void).
//  - output: hipMemsetAsync zeros + <=4 scatter stores/lane (r5 structure;
//    r6 showed NT stores hurt; r7 showed early-zero is not better).
__global__ __launch_bounds__(128)
void sparsemax_kernel(const float* __restrict__ x,
                      const float* __restrict__ m,
                      float* __restrict__ out) {
    const int lane = threadIdx.x & 63;
    const int wave = threadIdx.x >> 6;           // 0 or 1
    const int row  = blockIdx.x;

    __shared__ float  smax[2];
    __shared__ float2 sparts[2][2];              // [parity][wave] fallback partials
    __shared__ float  cand[CAP];                 // w = z - rmax of candidates
    __shared__ int    cnt;
    __shared__ int    sovf[2];                   // per-wave "some lane has >4"
    if (threadIdx.x == 0) cnt = 0;

    // Each wave owns half the row: 2048 elems = 512 float4, lane-strided.
    const size_t base = (size_t)row * (N / 4) + (size_t)wave * (N / 8);
    const float4* __restrict__ xr = (const float4*)x + base;
    const float4* __restrict__ mr = (const float4*)m + base;

    // BURST: issue all 16 loads back-to-back into distinct registers.
    // No consumption between issues -> ~16 global_load_dwordx4 in flight.
    float4 xv[8], mv[8];
#pragma unroll
    for (int j = 0; j < 8; ++j) xv[j] = xr[j * 64 + lane];
#pragma unroll
    for (int j = 0; j < 8; ++j) mv[j] = mr[j * 64 + lane];

    // Consume: z = (mask ? x : NEG_BIG) * 2   (/(1-TEMP), TEMP=0.5)
    float z[32];
    float rmax = -3.0e38f;
#pragma unroll
    for (int j = 0; j < 8; ++j) {
        float z0 = (mv[j].x != 0.0f ? xv[j].x : NEG_BIG) * 2.0f;
        float z1 = (mv[j].y != 0.0f ? xv[j].y : NEG_BIG) * 2.0f;
        float z2 = (mv[j].z != 0.0f ? xv[j].z : NEG_BIG) * 2.0f;
        float z3 = (mv[j].w != 0.0f ? xv[j].w : NEG_BIG) * 2.0f;
        z[4 * j + 0] = z0;
        z[4 * j + 1] = z1;
        z[4 * j + 2] = z2;
        z[4 * j + 3] = z3;
        rmax = fmaxf(rmax, fmaxf(fmaxf(z0, z1), fmaxf(z2, z3)));
    }

    // Wave-wide max butterfly, then cross-wave combine.
#pragma unroll
    for (int k = 32; k >= 1; k >>= 1)
        rmax = fmaxf(rmax, __shfl_xor(rmax, k, 64));
    if (lane == 0) smax[wave] = rmax;
    __syncthreads();                              // smax + cnt=0 visible
    rmax = fmaxf(smax[0], smax[1]);

    // Per-lane candidate pack WITH positions (static regs only, rule #20).
    // Support subset: sum_support(z - tau) = 1 => tau >= rmax - 1, and
    // candidates are exactly {z > rmax - 1}.
    const float thr0 = rmax - 1.0f;
    float lc0 = 0.0f, lc1 = 0.0f, lc2 = 0.0f, lc3 = 0.0f;
    int   lp0 = 0,    lp1 = 0,    lp2 = 0,    lp3 = 0;
    int lcnt = 0;
#pragma unroll
    for (int i = 0; i < 32; ++i) {
        if (z[i] > thr0) {
            float w = z[i] - rmax;
            int col = wave * (N / 2) + ((i >> 2) << 8) + (lane << 2) + (i & 3);
            lc0 = (lcnt == 0) ? w   : lc0;
            lp0 = (lcnt == 0) ? col : lp0;
            lc1 = (lcnt == 1) ? w   : lc1;
            lp1 = (lcnt == 1) ? col : lp1;
            lc2 = (lcnt == 2) ? w   : lc2;
            lp2 = (lcnt == 2) ? col : lp2;
            lc3 = (lcnt == 3) ? w   : lc3;
            lp3 = (lcnt == 3) ? col : lp3;
            ++lcnt;
        }
    }
    // One atomic per lane-with-candidates; values into shared list for Newton.
    int basei = 0;
    if (lcnt > 0) basei = atomicAdd(&cnt, lcnt);
    if (lcnt > 0 && basei + 0 < CAP) cand[basei + 0] = lc0;
    if (lcnt > 1 && basei + 1 < CAP) cand[basei + 1] = lc1;
    if (lcnt > 2 && basei + 2 < CAP) cand[basei + 2] = lc2;
    if (lcnt > 3 && basei + 3 < CAP) cand[basei + 3] = lc3;
    if (lane == 0) sovf[wave] = __any(lcnt > 4) ? 1 : 0;
    __syncthreads();                              // appends + flags visible

    const int  K   = cnt;                         // block-uniform
    const bool ovf = (sovf[0] | sovf[1]) != 0 || (K > CAP);
    float u = -1.0f;                              // solve sum max(w-u,0)=1

    if (!ovf && K <= 8) {
        // Broadcast candidates to registers; sentinel -2.0f never active
        // since u >= -1 throughout (v = -2 - u <= -1 < 0).
        float c0 = (0 < K) ? cand[0] : -2.0f;
        float c1 = (1 < K) ? cand[1] : -2.0f;
        float c2 = (2 < K) ? cand[2] : -2.0f;
        float c3 = (3 < K) ? cand[3] : -2.0f;
        float c4 = (4 < K) ? cand[4] : -2.0f;
        float c5 = (5 < K) ? cand[5] : -2.0f;
        float c6 = (6 < K) ? cand[6] : -2.0f;
        float c7 = (7 < K) ? cand[7] : -2.0f;
        for (int it = 0; it < 32; ++it) {
            float s = 0.0f, c = 0.0f;
#define SPMAX_ACC(cc) { float v = (cc) - u; if (v > 0.0f) { s += v; c += 1.0f; } }
            SPMAX_ACC(c0) SPMAX_ACC(c1) SPMAX_ACC(c2) SPMAX_ACC(c3)
            SPMAX_ACC(c4) SPMAX_ACC(c5) SPMAX_ACC(c6) SPMAX_ACC(c7)
#undef SPMAX_ACC
            float un = u + (s - 1.0f) / c;        // monotone non-decreasing
            if (!(un > u)) break;                 // exact fixed point
            u = un;
        }
    } else if (!ovf) {
        // Fat row: Newton over the LDS candidate list (broadcast reads).
        for (int it = 0; it < 32; ++it) {
            float s = 0.0f, c = 0.0f;
            for (int j = 0; j < K; ++j) {
                float v = cand[j] - u;
                if (v > 0.0f) { s += v; c += 1.0f; }
            }
            float un = u + (s - 1.0f) / c;
            if (!(un > u)) break;
            u = un;
        }
    } else {
        // Fallback over the full row (e.g. all-masked: all w == 0).
        // ovf is block-uniform; u sequence identical on both waves -> the
        // break is block-uniform. Parity double-buffer avoids a 2nd barrier.
        int parity = 0;
        for (int it = 0; it < 32; ++it) {
            float s = 0.0f, c = 0.0f;
#pragma unroll
            for (int i = 0; i < 32; ++i) {
                float v = (z[i] - rmax) - u;
                if (v > 0.0f) { s += v; c += 1.0f; }
            }
#pragma unroll
            for (int k = 32; k >= 1; k >>= 1) {
                s += __shfl_xor(s, k, 64);
                c += __shfl_xor(c, k, 64);
            }
            if (lane == 0) sparts[parity][wave] = make_float2(s, c);
            __syncthreads();
            float2 p0 = sparts[parity][0];
            float2 p1 = sparts[parity][1];
            float S = p0.x + p1.x;
            float C = p0.y + p1.y;
            float un = u + (S - 1.0f) / C;
            parity ^= 1;
            if (!(un > u)) break;
            u = un;
        }
    }

    if (!ovf) {
        // Scatter only the positive support entries; memset provided zeros.
        // out value = z - tau = (w + rmax) - (rmax + u) = w - u.
        float* __restrict__ orow = out + (size_t)row * N;
        if (lcnt > 0) { float v = lc0 - u; if (v > 0.0f) orow[lp0] = v; }
        if (lcnt > 1) { float v = lc1 - u; if (v > 0.0f) orow[lp1] = v; }
        if (lcnt > 2) { float v = lc2 - u; if (v > 0.0f) orow[lp2] = v; }
        if (lcnt > 3) { float v = lc3 - u; if (v > 0.0f) orow[lp3] = v; }
    } else {
        // Full-row store fallback. All-masked row: live=0 -> exact zeros.
        const float live = (rmax == NEG_BIG * 2.0f) ? 0.0f : 1.0f;
        const float thr  = rmax + u;              // = tau
        float4* __restrict__ outr = (float4*)out + base;
#pragma unroll
        for (int j = 0; j < 8; ++j) {
            float4 o;
            o.x = fmaxf(z[4 * j + 0] - thr, 0.0f) * live;
            o.y = fmaxf(z[4 * j + 1] - thr, 0.0f) * live;
            o.z = fmaxf(z[4 * j + 2] - thr, 0.0f) * live;
            o.w = fmaxf(z[4 * j + 3] - thr, 0.0f) * live;
            outr[j * 64 + lane] = o;
        }
    }
}

extern "C" void kernel_launch(void* const* d_in, const int* in_sizes, int n_in,
                              void* d_out, int out_size, void* d_ws, size_t ws_size,
                              hipStream_t stream) {
    const float* x = (const float*)d_in[0];
    const float* m = (const float*)d_in[1];
    float* out = (float*)d_out;
    const int rows = in_sizes[0] / N;             // 8192
    // Output is ~99.9% zeros: zero-fill at pure-write BW, then the kernel
    // scatter-writes only the support entries (round-5 best structure).
    hipMemsetAsync(d_out, 0, (size_t)out_size, stream);
    sparsemax_kernel<<<rows, 128, 0, stream>>>(x, m, out);
}

// Round 11
// 302.597 us; speedup vs baseline: 1.0312x; 1.0079x over previous
//
#include <hip/hip_runtime.h>

#define N 4096            // row length
#define NEG_BIG -9999999.9f
#define CAP 256           // candidate buffer capacity per row

typedef float floatx4 __attribute__((ext_vector_type(4)));

// v11: ISA-forced burst on the round-5 best (memset + scatter, 104 us).
// r10's source-level burst was VOID: compiler re-interleaved to stay at 48
// VGPR (cannot hold 16 float4 in flight). Here the 16 global_load_dwordx4
// are VOLATILE INLINE ASM (fixed order, 4-reg tuple dests held live),
// followed by s_waitcnt vmcnt(0) + sched_barrier(0) (rule #18: consume
// VALU must not hoist above the wait). ~4 KB in flight per wave vs ~256 B.
// Model A (outstanding-bytes cap) -> ~60-85 us; Model B (service cap) ->
// unchanged -> declare roofline next round.
__global__ __launch_bounds__(128)
void sparsemax_kernel(const float* __restrict__ x,
                      const float* __restrict__ m,
                      float* __restrict__ out) {
    const int lane = threadIdx.x & 63;
    const int wave = threadIdx.x >> 6;           // 0 or 1
    const int row  = blockIdx.x;

    __shared__ float  smax[2];
    __shared__ float2 sparts[2][2];              // [parity][wave] fallback partials
    __shared__ float  cand[CAP];                 // w = z - rmax of candidates
    __shared__ int    cnt;
    __shared__ int    sovf[2];                   // per-wave "some lane has >4"
    if (threadIdx.x == 0) cnt = 0;

    // Each wave owns half the row: 2048 elems = 512 float4, lane-strided.
    const size_t base = (size_t)row * (N / 4) + (size_t)wave * (N / 8);
    const float4* __restrict__ xr = (const float4*)x + base;
    const float4* __restrict__ mr = (const float4*)m + base;

    // Two bases per array; 13-bit offset immediates cover 4 x 1024 B each.
    const void* xa0 = (const void*)(xr + lane);         // j=0..3
    const void* xa1 = (const void*)(xr + 256 + lane);   // j=4..7
    const void* ma0 = (const void*)(mr + lane);
    const void* ma1 = (const void*)(mr + 256 + lane);

    floatx4 xv[8], mv[8];
#define SPMAX_LD(dst, baseptr, OFF)                                         \
    asm volatile("global_load_dwordx4 %0, %1, off offset:" OFF              \
                 : "=v"(dst) : "v"(baseptr) : "memory")
    SPMAX_LD(xv[0], xa0, "0");
    SPMAX_LD(xv[1], xa0, "1024");
    SPMAX_LD(xv[2], xa0, "2048");
    SPMAX_LD(xv[3], xa0, "3072");
    SPMAX_LD(xv[4], xa1, "0");
    SPMAX_LD(xv[5], xa1, "1024");
    SPMAX_LD(xv[6], xa1, "2048");
    SPMAX_LD(xv[7], xa1, "3072");
    SPMAX_LD(mv[0], ma0, "0");
    SPMAX_LD(mv[1], ma0, "1024");
    SPMAX_LD(mv[2], ma0, "2048");
    SPMAX_LD(mv[3], ma0, "3072");
    SPMAX_LD(mv[4], ma1, "0");
    SPMAX_LD(mv[5], ma1, "1024");
    SPMAX_LD(mv[6], ma1, "2048");
    SPMAX_LD(mv[7], ma1, "3072");
#undef SPMAX_LD
    asm volatile("s_waitcnt vmcnt(0)" ::: "memory");
    __builtin_amdgcn_sched_barrier(0);           // rule #18: pin consume below

    // Consume: z = (mask ? x : NEG_BIG) * 2   (/(1-TEMP), TEMP=0.5)
    float z[32];
    float rmax = -3.0e38f;
#pragma unroll
    for (int j = 0; j < 8; ++j) {
        float z0 = (mv[j].x != 0.0f ? xv[j].x : NEG_BIG) * 2.0f;
        float z1 = (mv[j].y != 0.0f ? xv[j].y : NEG_BIG) * 2.0f;
        float z2 = (mv[j].z != 0.0f ? xv[j].z : NEG_BIG) * 2.0f;
        float z3 = (mv[j].w != 0.0f ? xv[j].w : NEG_BIG) * 2.0f;
        z[4 * j + 0] = z0;
        z[4 * j + 1] = z1;
        z[4 * j + 2] = z2;
        z[4 * j + 3] = z3;
        rmax = fmaxf(rmax, fmaxf(fmaxf(z0, z1), fmaxf(z2, z3)));
    }

    // Wave-wide max butterfly, then cross-wave combine.
#pragma unroll
    for (int k = 32; k >= 1; k >>= 1)
        rmax = fmaxf(rmax, __shfl_xor(rmax, k, 64));
    if (lane == 0) smax[wave] = rmax;
    __syncthreads();                              // smax + cnt=0 visible
    rmax = fmaxf(smax[0], smax[1]);

    // Per-lane candidate pack WITH positions (static regs only, rule #20).
    // Support subset: sum_support(z - tau) = 1 => tau >= rmax - 1, and
    // candidates are exactly {z > rmax - 1}.
    const float thr0 = rmax - 1.0f;
    float lc0 = 0.0f, lc1 = 0.0f, lc2 = 0.0f, lc3 = 0.0f;
    int   lp0 = 0,    lp1 = 0,    lp2 = 0,    lp3 = 0;
    int lcnt = 0;
#pragma unroll
    for (int i = 0; i < 32; ++i) {
        if (z[i] > thr0) {
            float w = z[i] - rmax;
            int col = wave * (N / 2) + ((i >> 2) << 8) + (lane << 2) + (i & 3);
            lc0 = (lcnt == 0) ? w   : lc0;
            lp0 = (lcnt == 0) ? col : lp0;
            lc1 = (lcnt == 1) ? w   : lc1;
            lp1 = (lcnt == 1) ? col : lp1;
            lc2 = (lcnt == 2) ? w   : lc2;
            lp2 = (lcnt == 2) ? col : lp2;
            lc3 = (lcnt == 3) ? w   : lc3;
            lp3 = (lcnt == 3) ? col : lp3;
            ++lcnt;
        }
    }
    // One atomic per lane-with-candidates; values into shared list for Newton.
    int basei = 0;
    if (lcnt > 0) basei = atomicAdd(&cnt, lcnt);
    if (lcnt > 0 && basei + 0 < CAP) cand[basei + 0] = lc0;
    if (lcnt > 1 && basei + 1 < CAP) cand[basei + 1] = lc1;
    if (lcnt > 2 && basei + 2 < CAP) cand[basei + 2] = lc2;
    if (lcnt > 3 && basei + 3 < CAP) cand[basei + 3] = lc3;
    if (lane == 0) sovf[wave] = __any(lcnt > 4) ? 1 : 0;
    __syncthreads();                              // appends + flags visible

    const int  K   = cnt;                         // block-uniform
    const bool ovf = (sovf[0] | sovf[1]) != 0 || (K > CAP);
    float u = -1.0f;                              // solve sum max(w-u,0)=1

    if (!ovf && K <= 8) {
        // Broadcast candidates to registers; sentinel -2.0f never active
        // since u >= -1 throughout (v = -2 - u <= -1 < 0).
        float c0 = (0 < K) ? cand[0] : -2.0f;
        float c1 = (1 < K) ? cand[1] : -2.0f;
        float c2 = (2 < K) ? cand[2] : -2.0f;
        float c3 = (3 < K) ? cand[3] : -2.0f;
        float c4 = (4 < K) ? cand[4] : -2.0f;
        float c5 = (5 < K) ? cand[5] : -2.0f;
        float c6 = (6 < K) ? cand[6] : -2.0f;
        float c7 = (7 < K) ? cand[7] : -2.0f;
        for (int it = 0; it < 32; ++it) {
            float s = 0.0f, c = 0.0f;
#define SPMAX_ACC(cc) { float v = (cc) - u; if (v > 0.0f) { s += v; c += 1.0f; } }
            SPMAX_ACC(c0) SPMAX_ACC(c1) SPMAX_ACC(c2) SPMAX_ACC(c3)
            SPMAX_ACC(c4) SPMAX_ACC(c5) SPMAX_ACC(c6) SPMAX_ACC(c7)
#undef SPMAX_ACC
            float un = u + (s - 1.0f) / c;        // monotone non-decreasing
            if (!(un > u)) break;                 // exact fixed point
            u = un;
        }
    } else if (!ovf) {
        // Fat row: Newton over the LDS candidate list (broadcast reads).
        for (int it = 0; it < 32; ++it) {
            float s = 0.0f, c = 0.0f;
            for (int j = 0; j < K; ++j) {
                float v = cand[j] - u;
                if (v > 0.0f) { s += v; c += 1.0f; }
            }
            float un = u + (s - 1.0f) / c;
            if (!(un > u)) break;
            u = un;
        }
    } else {
        // Fallback over the full row (e.g. all-masked: all w == 0).
        // ovf is block-uniform; u sequence identical on both waves -> the
        // break is block-uniform. Parity double-buffer avoids a 2nd barrier.
        int parity = 0;
        for (int it = 0; it < 32; ++it) {
            float s = 0.0f, c = 0.0f;
#pragma unroll
            for (int i = 0; i < 32; ++i) {
                float v = (z[i] - rmax) - u;
                if (v > 0.0f) { s += v; c += 1.0f; }
            }
#pragma unroll
            for (int k = 32; k >= 1; k >>= 1) {
                s += __shfl_xor(s, k, 64);
                c += __shfl_xor(c, k, 64);
            }
            if (lane == 0) sparts[parity][wave] = make_float2(s, c);
            __syncthreads();
            float2 p0 = sparts[parity][0];
            float2 p1 = sparts[parity][1];
            float S = p0.x + p1.x;
            float C = p0.y + p1.y;
            float un = u + (S - 1.0f) / C;
            parity ^= 1;
            if (!(un > u)) break;
            u = un;
        }
    }

    if (!ovf) {
        // Scatter only the positive support entries; memset provided zeros.
        // out value = z - tau = (w + rmax) - (rmax + u) = w - u.
        float* __restrict__ orow = out + (size_t)row * N;
        if (lcnt > 0) { float v = lc0 - u; if (v > 0.0f) orow[lp0] = v; }
        if (lcnt > 1) { float v = lc1 - u; if (v > 0.0f) orow[lp1] = v; }
        if (lcnt > 2) { float v = lc2 - u; if (v > 0.0f) orow[lp2] = v; }
        if (lcnt > 3) { float v = lc3 - u; if (v > 0.0f) orow[lp3] = v; }
    } else {
        // Full-row store fallback. All-masked row: live=0 -> exact zeros.
        const float live = (rmax == NEG_BIG * 2.0f) ? 0.0f : 1.0f;
        const float thr  = rmax + u;              // = tau
        float4* __restrict__ outr = (float4*)out + base;
#pragma unroll
        for (int j = 0; j < 8; ++j) {
            float4 o;
            o.x = fmaxf(z[4 * j + 0] - thr, 0.0f) * live;
            o.y = fmaxf(z[4 * j + 1] - thr, 0.0f) * live;
            o.z = fmaxf(z[4 * j + 2] - thr, 0.0f) * live;
            o.w = fmaxf(z[4 * j + 3] - thr, 0.0f) * live;
            outr[j * 64 + lane] = o;
        }
    }
}

extern "C" void kernel_launch(void* const* d_in, const int* in_sizes, int n_in,
                              void* d_out, int out_size, void* d_ws, size_t ws_size,
                              hipStream_t stream) {
    const float* x = (const float*)d_in[0];
    const float* m = (const float*)d_in[1];
    float* out = (float*)d_out;
    const int rows = in_sizes[0] / N;             // 8192
    // Output is ~99.9% zeros: zero-fill at pure-write BW, then the kernel
    // scatter-writes only the support entries (round-5 best structure).
    hipMemsetAsync(d_out, 0, (size_t)out_size, stream);
    sparsemax_kernel<<<rows, 128, 0, stream>>>(x, m, out);
}

// Round 12
// 299.936 us; speedup vs baseline: 1.0403x; 1.0089x over previous
//
#include <hip/hip_runtime.h>

#define N 4096            // row length
#define NEG_BIG -9999999.9f
#define CAP 256           // candidate buffer capacity per row

// v12: direct-to-LDS staging experiment (final Model A/B discriminator).
// r10/r11 showed register-dest load bursts CANNOT be forced deep: the
// allocator serializes them to stay at ~40-48 VGPR (r11: VGPR=40 cannot
// hold 16 float4 dests -> asm burst was silently serialized).
// global_load_lds has NO dest VGPR -> issue depth is decoupled from
// register pressure; 8 fire-and-forget dwordx4 per wave (8 KB in flight
// vs ~256 B before). 256-thr blocks (4 waves/row), 32 KB LDS staging ->
// 4 blocks/CU = 16 waves/CU (== current residency, so occupancy is held
// constant while in-flight bytes go up ~30x: clean single-variable test).
// The vmcnt(0) hipcc emits before __syncthreads is WANTED here: full row
// must land before the max phase. Output: r5 best (memset + scatter).
__device__ __forceinline__ void ld_lds16(const float4* g, float4* l) {
    __builtin_amdgcn_global_load_lds(
        (const __attribute__((address_space(1))) void*)g,
        (__attribute__((address_space(3))) void*)l, 16, 0, 0);
}

__global__ __launch_bounds__(256)
void sparsemax_kernel(const float* __restrict__ x,
                      const float* __restrict__ m,
                      float* __restrict__ out) {
    const int t    = (int)threadIdx.x;            // 0..255
    const int lane = t & 63;
    const int wid  = t >> 6;                      // 0..3
    const int row  = blockIdx.x;

    __shared__ float  sx[N];                      // 16 KB staged x row
    __shared__ float  sm[N];                      // 16 KB staged m row
    __shared__ float  smax4[4];
    __shared__ float2 sparts[2][4];               // [parity][wave] fallback
    __shared__ float  cand[CAP];                  // w = z - rmax candidates
    __shared__ int    cnt;
    __shared__ int    sovf[4];                    // per-wave ">4 cands" flag
    if (t == 0) cnt = 0;

    const float4* __restrict__ x4 = (const float4*)x + (size_t)row * (N / 4);
    const float4* __restrict__ m4 = (const float4*)m + (size_t)row * (N / 4);
    float4* sx4 = (float4*)sx;
    float4* sm4 = (float4*)sm;

    // Wave wid stages row float4-slots [wid*256, wid*256+256): 8 async
    // direct-to-LDS loads, all in flight at once (no dest registers).
    // LDS dest is wave-uniform base + lane*16B (linear) = global layout.
#pragma unroll
    for (int k = 0; k < 4; ++k) {
        const int slot = wid * 256 + k * 64;      // wave-uniform slot base
        ld_lds16(x4 + slot + lane, sx4 + slot);
        ld_lds16(m4 + slot + lane, sm4 + slot);
    }

    __syncthreads();                              // vmcnt(0) drain: row staged

    // Consume from LDS: thread t owns float4 slots {t + 256k, k=0..3}.
    // z = (mask ? x : NEG_BIG) * 2   (/(1-TEMP), TEMP=0.5)
    float z[16];
    float tmax = -3.0e38f;
#pragma unroll
    for (int k = 0; k < 4; ++k) {
        float4 xv = sx4[t + 256 * k];
        float4 mv = sm4[t + 256 * k];
        float z0 = (mv.x != 0.0f ? xv.x : NEG_BIG) * 2.0f;
        float z1 = (mv.y != 0.0f ? xv.y : NEG_BIG) * 2.0f;
        float z2 = (mv.z != 0.0f ? xv.z : NEG_BIG) * 2.0f;
        float z3 = (mv.w != 0.0f ? xv.w : NEG_BIG) * 2.0f;
        z[4 * k + 0] = z0;
        z[4 * k + 1] = z1;
        z[4 * k + 2] = z2;
        z[4 * k + 3] = z3;
        tmax = fmaxf(tmax, fmaxf(fmaxf(z0, z1), fmaxf(z2, z3)));
    }

    // Wave butterfly, then 4-wave combine via LDS.
    float rmax = tmax;
#pragma unroll
    for (int k = 32; k >= 1; k >>= 1)
        rmax = fmaxf(rmax, __shfl_xor(rmax, k, 64));
    if (lane == 0) smax4[wid] = rmax;
    __syncthreads();
    rmax = fmaxf(fmaxf(smax4[0], smax4[1]), fmaxf(smax4[2], smax4[3]));

    // Per-lane candidate pack WITH positions (static regs only, rule #20).
    // Support subset: sum_support(z - tau) = 1 => tau >= rmax - 1, and
    // candidates are exactly {z > rmax - 1}.
    const float thr0 = rmax - 1.0f;
    float lc0 = 0.0f, lc1 = 0.0f, lc2 = 0.0f, lc3 = 0.0f;
    int   lp0 = 0,    lp1 = 0,    lp2 = 0,    lp3 = 0;
    int lcnt = 0;
#pragma unroll
    for (int i = 0; i < 16; ++i) {
        if (z[i] > thr0) {
            float w = z[i] - rmax;
            int col = (t + 256 * (i >> 2)) * 4 + (i & 3);  // scalar column
            lc0 = (lcnt == 0) ? w   : lc0;
            lp0 = (lcnt == 0) ? col : lp0;
            lc1 = (lcnt == 1) ? w   : lc1;
            lp1 = (lcnt == 1) ? col : lp1;
            lc2 = (lcnt == 2) ? w   : lc2;
            lp2 = (lcnt == 2) ? col : lp2;
            lc3 = (lcnt == 3) ? w   : lc3;
            lp3 = (lcnt == 3) ? col : lp3;
            ++lcnt;
        }
    }
    // One atomic per lane-with-candidates; values into shared list for Newton.
    int basei = 0;
    if (lcnt > 0) basei = atomicAdd(&cnt, lcnt);
    if (lcnt > 0 && basei + 0 < CAP) cand[basei + 0] = lc0;
    if (lcnt > 1 && basei + 1 < CAP) cand[basei + 1] = lc1;
    if (lcnt > 2 && basei + 2 < CAP) cand[basei + 2] = lc2;
    if (lcnt > 3 && basei + 3 < CAP) cand[basei + 3] = lc3;
    if (lane == 0) sovf[wid] = __any(lcnt > 4) ? 1 : 0;
    __syncthreads();                              // appends + flags visible

    const int  K   = cnt;                         // block-uniform
    const bool ovf = (sovf[0] | sovf[1] | sovf[2] | sovf[3]) != 0 || (K > CAP);
    float u = -1.0f;                              // solve sum max(w-u,0)=1

    if (!ovf && K <= 8) {
        // Broadcast candidates to registers; sentinel -2.0f never active
        // since u >= -1 throughout (v = -2 - u <= -1 < 0).
        float c0 = (0 < K) ? cand[0] : -2.0f;
        float c1 = (1 < K) ? cand[1] : -2.0f;
        float c2 = (2 < K) ? cand[2] : -2.0f;
        float c3 = (3 < K) ? cand[3] : -2.0f;
        float c4 = (4 < K) ? cand[4] : -2.0f;
        float c5 = (5 < K) ? cand[5] : -2.0f;
        float c6 = (6 < K) ? cand[6] : -2.0f;
        float c7 = (7 < K) ? cand[7] : -2.0f;
        for (int it = 0; it < 32; ++it) {
            float s = 0.0f, c = 0.0f;
#define SPMAX_ACC(cc) { float v = (cc) - u; if (v > 0.0f) { s += v; c += 1.0f; } }
            SPMAX_ACC(c0) SPMAX_ACC(c1) SPMAX_ACC(c2) SPMAX_ACC(c3)
            SPMAX_ACC(c4) SPMAX_ACC(c5) SPMAX_ACC(c6) SPMAX_ACC(c7)
#undef SPMAX_ACC
            float un = u + (s - 1.0f) / c;        // monotone non-decreasing
            if (!(un > u)) break;                 // exact fixed point
            u = un;
        }
    } else if (!ovf) {
        // Fat row: Newton over the LDS candidate list (broadcast reads).
        for (int it = 0; it < 32; ++it) {
            float s = 0.0f, c = 0.0f;
            for (int j = 0; j < K; ++j) {
                float v = cand[j] - u;
                if (v > 0.0f) { s += v; c += 1.0f; }
            }
            float un = u + (s - 1.0f) / c;
            if (!(un > u)) break;
            u = un;
        }
    } else {
        // Fallback over the full row (e.g. all-masked: all w == 0).
        // ovf is block-uniform; u sequence identical on all waves -> the
        // break is block-uniform. Parity double-buffer: one barrier/iter.
        int parity = 0;
        for (int it = 0; it < 32; ++it) {
            float s = 0.0f, c = 0.0f;
#pragma unroll
            for (int i = 0; i < 16; ++i) {
                float v = (z[i] - rmax) - u;
                if (v > 0.0f) { s += v; c += 1.0f; }
            }
#pragma unroll
            for (int k = 32; k >= 1; k >>= 1) {
                s += __shfl_xor(s, k, 64);
                c += __shfl_xor(c, k, 64);
            }
            if (lane == 0) sparts[parity][wid] = make_float2(s, c);
            __syncthreads();
            float S = sparts[parity][0].x + sparts[parity][1].x
                    + sparts[parity][2].x + sparts[parity][3].x;
            float C = sparts[parity][0].y + sparts[parity][1].y
                    + sparts[parity][2].y + sparts[parity][3].y;
            float un = u + (S - 1.0f) / C;
            parity ^= 1;
            if (!(un > u)) break;
            u = un;
        }
    }

    if (!ovf) {
        // Scatter only the positive support entries; memset provided zeros.
        // out value = z - tau = (w + rmax) - (rmax + u) = w - u.
        float* __restrict__ orow = out + (size_t)row * N;
        if (lcnt > 0) { float v = lc0 - u; if (v > 0.0f) orow[lp0] = v; }
        if (lcnt > 1) { float v = lc1 - u; if (v > 0.0f) orow[lp1] = v; }
        if (lcnt > 2) { float v = lc2 - u; if (v > 0.0f) orow[lp2] = v; }
        if (lcnt > 3) { float v = lc3 - u; if (v > 0.0f) orow[lp3] = v; }
    } else {
        // Full-row store fallback. All-masked row: live=0 -> exact zeros.
        const float live = (rmax == NEG_BIG * 2.0f) ? 0.0f : 1.0f;
        const float thr  = rmax + u;              // = tau
        float4* __restrict__ out4 = (float4*)out + (size_t)row * (N / 4);
#pragma unroll
        for (int k = 0; k < 4; ++k) {
            float4 o;
            o.x = fmaxf(z[4 * k + 0] - thr, 0.0f) * live;
            o.y = fmaxf(z[4 * k + 1] - thr, 0.0f) * live;
            o.z = fmaxf(z[4 * k + 2] - thr, 0.0f) * live;
            o.w = fmaxf(z[4 * k + 3] - thr, 0.0f) * live;
            out4[t + 256 * k] = o;
        }
    }
}

extern "C" void kernel_launch(void* const* d_in, const int* in_sizes, int n_in,
                              void* d_out, int out_size, void* d_ws, size_t ws_size,
                              hipStream_t stream) {
    const float* x = (const float*)d_in[0];
    const float* m = (const float*)d_in[1];
    float* out = (float*)d_out;
    const int rows = in_sizes[0] / N;             // 8192
    // Output is ~99.9% zeros: zero-fill at pure-write BW, then the kernel
    // scatter-writes only the support entries (round-5 best structure).
    hipMemsetAsync(d_out, 0, (size_t)out_size, stream);
    sparsemax_kernel<<<rows, 256, 0, stream>>>(x, m, out);
}